// Round 4
// baseline (596.888 us; speedup 1.0000x reference)
//
#include <hip/hip_runtime.h>
#include <hip/hip_bf16.h>
#include <stdint.h>

// GCN layer: out = relu(segment_sum(dropout(x)[src]*w, dst) @ W + b)
// N=50000 nodes, E=800000 edges (dst SORTED), F=512 in/out feats.
//
// Pipeline (v4):
//  1) prep_kernel : fused grid-partitioned
//                   [blk 0..12499]     dropout threefry -> xd bf16 PLANE-SLICED
//                                      xd[16 planes][50000 nodes][32 feats]
//                   [blk 12500..13523] W fp32 [k][n] -> WbT bf16 [n][k]
//                                      (block 12500 also zeroes cnt[8])
//                   [blk 13524..16649] CSR rowptr from sorted edge_dst
//  2) agg_kernel  : XCD-affine gather via RUNTIME XCC_ID (not blockIdx%8 —
//                   r2 proved that mapping does not hold). Persistent 2048
//                   blocks; per-XCD atomic chunk queue; each XCD processes
//                   slices {xcc, xcc+8} = two 3.2MB planes (fit 4MB L2).
//                   Inner loop = r2's proven 4-lane-group gather ladder.
//                   Correct under ANY dispatch: blocks drain the queue of
//                   whatever XCD they landed on (G16-safe).
//  3) gemm_kernel : MFMA bf16 GEMM, 128x256 tile, 512 thr — v1 measured-best.
//
// [r3 lesson: agg+gemm fusion is net-negative — gather is latency-bound, not
//  BW-bound; deleting 150MB of spill traffic bought nothing and the barrier
//  + 2-blocks/CU LDS cap slowed the gather 1.5x.]

#define N_NODESC 50000
#define N_EDGESC 800000
#define FEATS    512
#define TOT_ELEMS (N_NODESC * FEATS)   // 25,600,000

#define PLANE_STRIDE (N_NODESC * 32)   // u16 elems per 32-feat plane (3.2 MB)

#define DROP_BLKS   12500              // 25.6M / (256*8)
#define WCONV_BLKS  1024               // 262144 / 256
#define ROWP_BLKS   3126               // ceil(800001/256)
#define PREP_BLKS   (DROP_BLKS + WCONV_BLKS + ROWP_BLKS)

#define AGG_GRID         2048          // persistent; 8 blocks/CU
#define CHUNKS_PER_SLICE 782           // ceil(50000/64) 64-node chunks
#define CHUNKS_PER_XCD   (2 * CHUNKS_PER_SLICE)

typedef unsigned int u32;
typedef unsigned short u16;
typedef __attribute__((ext_vector_type(8))) short short8;
typedef __attribute__((ext_vector_type(4))) float floatx4;
typedef __attribute__((ext_vector_type(4))) u32 uintx4;

__device__ __forceinline__ void tf_round(u32& a, u32& b, int r) {
  a += b;
  b = (b << r) | (b >> (32 - r));
  b ^= a;
}

// Threefry-2x32, 20 rounds, key = (0, 42)  — bit-exact vs jax; DO NOT TOUCH.
__device__ __forceinline__ void threefry(u32& x0, u32& x1) {
  const u32 k0 = 0u, k1 = 42u, k2 = 0x1BD11BDAu ^ 0u ^ 42u;
  x0 += k0; x1 += k1;
  tf_round(x0,x1,13); tf_round(x0,x1,15); tf_round(x0,x1,26); tf_round(x0,x1,6);
  x0 += k1; x1 += k2 + 1u;
  tf_round(x0,x1,17); tf_round(x0,x1,29); tf_round(x0,x1,16); tf_round(x0,x1,24);
  x0 += k2; x1 += k0 + 2u;
  tf_round(x0,x1,13); tf_round(x0,x1,15); tf_round(x0,x1,26); tf_round(x0,x1,6);
  x0 += k0; x1 += k1 + 3u;
  tf_round(x0,x1,17); tf_round(x0,x1,29); tf_round(x0,x1,16); tf_round(x0,x1,24);
  x0 += k1; x1 += k2 + 4u;
  tf_round(x0,x1,13); tf_round(x0,x1,15); tf_round(x0,x1,26); tf_round(x0,x1,6);
  x0 += k2; x1 += k0 + 5u;
}

__device__ __forceinline__ u16 f2bf(float f) {  // RNE float->bf16
  u32 u = __float_as_uint(f);
  u32 r = (u + 0x7FFFu + ((u >> 16) & 1u)) >> 16;
  return (u16)r;
}

// 1) fused prep: dropout (plane-sliced) | W transpose+cast | CSR rowptr | cnt=0
__global__ __launch_bounds__(256) void prep_kernel(const float* __restrict__ x,
                                                   u16* __restrict__ xd,
                                                   const float* __restrict__ W,
                                                   u16* __restrict__ WbT,
                                                   const int* __restrict__ dst,
                                                   int* __restrict__ rowptr,
                                                   int* __restrict__ cnt) {
  int b = blockIdx.x;
  if (b < DROP_BLKS) {
    // dropout: 8 consecutive flat elements per thread (RNG index = flat index)
    int t = b * 256 + threadIdx.x;
    int j0 = t * 8;
    float4 xa = *(const float4*)(x + j0);
    float4 xb = *(const float4*)(x + j0 + 4);
    float xs[8] = {xa.x, xa.y, xa.z, xa.w, xb.x, xb.y, xb.z, xb.w};
    u16 r[8];
#pragma unroll
    for (int q = 0; q < 8; ++q) {
      u32 a = 0u, c = (u32)(j0 + q);
      threefry(a, c);
      u32 bits = a ^ c;
      float u = __uint_as_float((bits >> 9) | 0x3F800000u) - 1.0f;  // [0,1)
      float m = (u < 0.9f) ? (1.0f / 0.9f) : 0.0f;
      r[q] = f2bf(xs[q] * m);
    }
    uint4 o;
    o.x = (u32)r[0] | ((u32)r[1] << 16);
    o.y = (u32)r[2] | ((u32)r[3] << 16);
    o.z = (u32)r[4] | ((u32)r[5] << 16);
    o.w = (u32)r[6] | ((u32)r[7] << 16);
    // plane-sliced store: plane = f0/32, row = node (64B per row-slice)
    int node = j0 >> 9;
    int f0 = j0 & 511;
    *(uint4*)(xd + (size_t)(f0 >> 5) * PLANE_STRIDE + node * 32 + (f0 & 31)) = o;
  } else if (b < DROP_BLKS + WCONV_BLKS) {
    // W [k][n] fp32 -> WbT [n][k] bf16
    if (b == DROP_BLKS && threadIdx.x < 8) cnt[threadIdx.x] = 0;  // queue reset
    int t = (b - DROP_BLKS) * 256 + threadIdx.x;   // 0..262143
    int k = t >> 9, n = t & 511;
    WbT[n * 512 + k] = f2bf(W[t]);
  } else {
    // CSR rowptr from sorted dst (covers [0,N] exactly once)
    int e = (b - DROP_BLKS - WCONV_BLKS) * 256 + threadIdx.x;
    if (e > N_EDGESC) return;
    int d  = (e < N_EDGESC) ? dst[e] : N_NODESC;
    int pd = (e > 0) ? dst[e - 1] : -1;
    for (int n = pd + 1; n <= d; ++n) rowptr[n] = e;
  }
}

// 2) aggregation v4: persistent XCD-pinned feature-sliced gather.
//    Block: 256 thr = 4 waves; wave = 16 nodes (4-lane group per node),
//    each group gathers its node's 64B slice per edge (uint4/lane).
__device__ __forceinline__ void agg_fma(float* acc, float w, const uint4& v) {
  u32 a[4] = {v.x, v.y, v.z, v.w};
#pragma unroll
  for (int p = 0; p < 4; ++p) {
    acc[2*p]   += w * __uint_as_float(a[p] << 16);
    acc[2*p+1] += w * __uint_as_float(a[p] & 0xFFFF0000u);
  }
}

__global__ __launch_bounds__(256) void agg_kernel(const u16* __restrict__ xd,
                                                  const float* __restrict__ ew,
                                                  const int* __restrict__ src,
                                                  const int* __restrict__ rowptr,
                                                  u16* __restrict__ agg,
                                                  int* __restrict__ cnt) {
  u32 xcc;
  asm volatile("s_getreg_b32 %0, hwreg(HW_REG_XCC_ID)" : "=s"(xcc));
  xcc &= 7u;

  const int wv   = threadIdx.x >> 6;
  const int lane = threadIdx.x & 63;
  const int grp  = lane >> 2;               // node within wave: 0..15
  const int fl   = lane & 3;                // 16B chunk within 64B slice

  __shared__ int s_chunk;

  for (;;) {
    __syncthreads();
    if (threadIdx.x == 0) s_chunk = atomicAdd(&cnt[xcc], 1);
    __syncthreads();
    int c = s_chunk;
    if (c >= CHUNKS_PER_XCD) break;         // block-uniform exit

    int slice, g;
    if (c < CHUNKS_PER_SLICE) { slice = (int)xcc;     g = c; }
    else                      { slice = (int)xcc + 8; g = c - CHUNKS_PER_SLICE; }

    const int n = g * 64 + wv * 16 + grp;
    int lo = 0, hi = 0;
    if (n < N_NODESC) { lo = rowptr[n]; hi = rowptr[n + 1]; }

    const u16* plane = xd + (size_t)slice * PLANE_STRIDE;
    float acc[8] = {0.f,0.f,0.f,0.f,0.f,0.f,0.f,0.f};

    // 8-deep predicated gather ladder; per-lane edge range, wave-uniform exit.
    for (int e0 = lo; __any(e0 < hi); e0 += 8) {
      uint4 v[8]; float w[8];
#pragma unroll
      for (int q = 0; q < 8; ++q) {
        int e = e0 + q;
        v[q] = (uint4){0u,0u,0u,0u};
        w[q] = 0.0f;
        if (e < hi) {
          int s = __builtin_nontemporal_load(src + e);   // nt: keep plane in L2
          w[q] = __builtin_nontemporal_load(ew + e);
          v[q] = *(const uint4*)(plane + (size_t)s * 32 + fl * 8);
        }
      }
#pragma unroll
      for (int q = 0; q < 8; ++q) agg_fma(acc, w[q], v[q]);
    }

    if (n < N_NODESC) {
      uintx4 o;
      o.x = (u32)f2bf(acc[0]) | ((u32)f2bf(acc[1]) << 16);
      o.y = (u32)f2bf(acc[2]) | ((u32)f2bf(acc[3]) << 16);
      o.z = (u32)f2bf(acc[4]) | ((u32)f2bf(acc[5]) << 16);
      o.w = (u32)f2bf(acc[6]) | ((u32)f2bf(acc[7]) << 16);
      // agg stays row-major [node][512] for GEMM; nt store: don't evict plane
      __builtin_nontemporal_store(o,
          (uintx4*)(agg + (size_t)n * 512 + slice * 32 + fl * 8));
    }
  }
}

// 3) GEMM: C[M,512] = A[M,512](bf16) * B^T ; relu(+bias).  (v1 measured-best)
#define BM 128
#define BN 256
#define BK 64

__global__ __launch_bounds__(512, 4) void gemm_kernel(const u16* __restrict__ A,
                                                      const u16* __restrict__ BT,
                                                      const float* __restrict__ bias,
                                                      float* __restrict__ out) {
  __shared__ __align__(16) u16 Asm[BM * BK];   // 16 KB
  __shared__ __align__(16) u16 Bsm[BN * BK];   // 32 KB

  const int tid  = threadIdx.x;
  const int lane = tid & 63;
  const int w    = tid >> 6;          // 0..7
  const int m0 = blockIdx.x * BM;
  const int n0 = blockIdx.y * BN;
  const int wm = (w >> 2) * 64;       // 0,64
  const int wn = (w & 3) * 64;        // 0,64,128,192
  const int lm   = lane & 15;
  const int quad = lane >> 4;
  const int lrow = lane >> 3;        // 0..7
  const int lcol = (lane & 7) * 8;   // bf16 elems

  floatx4 acc[4][4];
#pragma unroll
  for (int i = 0; i < 4; ++i)
#pragma unroll
    for (int j = 0; j < 4; ++j) acc[i][j] = (floatx4)0.0f;

  for (int k0 = 0; k0 < 512; k0 += BK) {
    // A: 16 chunks (8 rows x 64 cols = 1 KB each); 8 waves x 2
#pragma unroll
    for (int t = 0; t < 2; ++t) {
      int chunk = w * 2 + t;              // 0..15
      int row = chunk * 8 + lrow;         // 0..127
      int gm = m0 + row;
      if (gm > N_NODESC - 1) gm = N_NODESC - 1;
      __builtin_amdgcn_global_load_lds(
          (const __attribute__((address_space(1))) void*)(A + (size_t)gm * 512 + k0 + lcol),
          (__attribute__((address_space(3))) void*)((char*)Asm + chunk * 1024),
          16, 0, 0);
    }
    // B: 32 chunks; 8 waves x 4
#pragma unroll
    for (int t = 0; t < 4; ++t) {
      int chunk = w * 4 + t;              // 0..31
      int row = chunk * 8 + lrow;         // 0..255
      __builtin_amdgcn_global_load_lds(
          (const __attribute__((address_space(1))) void*)(BT + (size_t)(n0 + row) * 512 + k0 + lcol),
          (__attribute__((address_space(3))) void*)((char*)Bsm + chunk * 1024),
          16, 0, 0);
    }
    __syncthreads();

#pragma unroll
    for (int kk = 0; kk < BK; kk += 32) {
      short8 af[4], bfr[4];
#pragma unroll
      for (int i = 0; i < 4; ++i)
        af[i] = *(const short8*)(Asm + (wm + i * 16 + lm) * BK + kk + quad * 8);
#pragma unroll
      for (int j = 0; j < 4; ++j)
        bfr[j] = *(const short8*)(Bsm + (wn + j * 16 + lm) * BK + kk + quad * 8);
#pragma unroll
      for (int i = 0; i < 4; ++i)
#pragma unroll
        for (int j = 0; j < 4; ++j)
          acc[i][j] = __builtin_amdgcn_mfma_f32_16x16x32_bf16(af[i], bfr[j], acc[i][j], 0, 0, 0);
    }
    __syncthreads();
  }

  // epilogue: C/D layout col=lane&15, row=quad*4+r
#pragma unroll
  for (int j = 0; j < 4; ++j) {
    int col = n0 + wn + j * 16 + lm;
    float bv = bias[col];
#pragma unroll
    for (int i = 0; i < 4; ++i) {
      int row0 = m0 + wm + i * 16 + quad * 4;
#pragma unroll
      for (int r = 0; r < 4; ++r) {
        int row = row0 + r;
        if (row < N_NODESC) {
          float v = acc[i][j][r] + bv;
          out[(size_t)row * 512 + col] = v > 0.0f ? v : 0.0f;
        }
      }
    }
  }
}

extern "C" void kernel_launch(void* const* d_in, const int* in_sizes, int n_in,
                              void* d_out, int out_size, void* d_ws, size_t ws_size,
                              hipStream_t stream) {
  const float* x  = (const float*)d_in[0];
  const float* ew = (const float*)d_in[1];
  const float* W  = (const float*)d_in[2];
  const float* b  = (const float*)d_in[3];
  const int* esrc = (const int*)d_in[4];
  const int* edst = (const int*)d_in[5];
  float* out = (float*)d_out;

  char* ws = (char*)d_ws;
  u16* xd    = (u16*)ws;                                   // 51.2 MB (16 planes)
  u16* agg   = (u16*)(ws + (size_t)TOT_ELEMS * 2);         // 51.2 MB
  u16* WbT   = (u16*)(ws + (size_t)TOT_ELEMS * 4);         // 0.5 MB
  int* rowp  = (int*)(ws + (size_t)TOT_ELEMS * 4 + 512 * 512 * 2);            // 200 KB
  int* cnt   = (int*)(ws + (size_t)TOT_ELEMS * 4 + 512 * 512 * 2 + 200064);   // 32 B
  (void)ws_size; (void)n_in; (void)in_sizes; (void)out_size;

  hipLaunchKernelGGL(prep_kernel,  dim3(PREP_BLKS), dim3(256), 0, stream,
                     x, xd, W, WbT, edst, rowp, cnt);
  hipLaunchKernelGGL(agg_kernel,   dim3(AGG_GRID), dim3(256), 0, stream,
                     xd, ew, esrc, rowp, agg, cnt);
  hipLaunchKernelGGL(gemm_kernel,  dim3((N_NODESC + BM - 1) / BM, 512 / BN), dim3(512), 0, stream,
                     agg, WbT, b, out);
}

// Round 7
// 373.182 us; speedup vs baseline: 1.5995x; 1.5995x over previous
//
#include <hip/hip_runtime.h>
#include <hip/hip_bf16.h>
#include <stdint.h>

// GCN layer: out = relu(segment_sum(dropout(x)[src]*w, dst) @ W + b)
// N=50000 nodes, E=800000 edges (dst SORTED), F=512 in/out feats.
//
// Pipeline (v6):
//  1) prep_kernel : fused grid-partitioned
//                   [blk 0..12499]     dropout threefry -> xd bf16 [N,512] LINEAR
//                   [blk 12500..13523] W fp32 [k][n] -> WbT bf16 [n][k]
//                   [blk 13524..16649] CSR rowptr from sorted edge_dst
//  2) agg_kernel  : v1's wave-per-node full-row gather (1KB coalesced reads,
//                   8-deep MLP ladder) on a PERSISTENT 2048-block grid with
//                   STATIC strided wave->node assignment (wave g of 8192 does
//                   nodes g, g+8192, ...). No atomics, no global state, no
//                   dispatch-rate dependence, replay/graph-capture safe.
//                   [v1: 35% occupancy, 3.9TB/s, 112us with nothing capping
//                    occupancy -> theory: dispatch/turnover limited.]
//  3) gemm_kernel : MFMA bf16 GEMM, 128x256 tile, 512 thr — v1 measured-best.
//
// [r2/r4 lesson: feature-sliced XCD-affine gather triple-refuted — 3.2MB plane
//  at 80% of L2 does NOT stay resident under streaming interference.]
// [r3 lesson: agg+gemm fusion net-negative (LDS cap + barrier serialization).]
// [r5/r6 lesson: persistent-with-atomic-queue kernel coincided with container
//  failures; replaced with stateless static striding — same occupancy theory.]

#define N_NODESC 50000
#define N_EDGESC 800000
#define FEATS    512
#define TOT_ELEMS (N_NODESC * FEATS)   // 25,600,000

#define DROP_BLKS   12500              // 25.6M / (256*8)
#define WCONV_BLKS  1024               // 262144 / 256
#define ROWP_BLKS   3126               // ceil(800001/256)
#define PREP_BLKS   (DROP_BLKS + WCONV_BLKS + ROWP_BLKS)

#define AGG_GRID    2048               // persistent; 8 blocks/CU
#define AGG_WAVES   (AGG_GRID * 4)     // 8192 waves, ~6.1 nodes each

typedef unsigned int u32;
typedef unsigned short u16;
typedef __attribute__((ext_vector_type(8))) short short8;
typedef __attribute__((ext_vector_type(4))) float floatx4;

__device__ __forceinline__ void tf_round(u32& a, u32& b, int r) {
  a += b;
  b = (b << r) | (b >> (32 - r));
  b ^= a;
}

// Threefry-2x32, 20 rounds, key = (0, 42)  — bit-exact vs jax; DO NOT TOUCH.
__device__ __forceinline__ void threefry(u32& x0, u32& x1) {
  const u32 k0 = 0u, k1 = 42u, k2 = 0x1BD11BDAu ^ 0u ^ 42u;
  x0 += k0; x1 += k1;
  tf_round(x0,x1,13); tf_round(x0,x1,15); tf_round(x0,x1,26); tf_round(x0,x1,6);
  x0 += k1; x1 += k2 + 1u;
  tf_round(x0,x1,17); tf_round(x0,x1,29); tf_round(x0,x1,16); tf_round(x0,x1,24);
  x0 += k2; x1 += k0 + 2u;
  tf_round(x0,x1,13); tf_round(x0,x1,15); tf_round(x0,x1,26); tf_round(x0,x1,6);
  x0 += k0; x1 += k1 + 3u;
  tf_round(x0,x1,17); tf_round(x0,x1,29); tf_round(x0,x1,16); tf_round(x0,x1,24);
  x0 += k1; x1 += k2 + 4u;
  tf_round(x0,x1,13); tf_round(x0,x1,15); tf_round(x0,x1,26); tf_round(x0,x1,6);
  x0 += k2; x1 += k0 + 5u;
}

__device__ __forceinline__ u16 f2bf(float f) {  // RNE float->bf16
  u32 u = __float_as_uint(f);
  u32 r = (u + 0x7FFFu + ((u >> 16) & 1u)) >> 16;
  return (u16)r;
}

// 1) fused prep: dropout | W transpose+cast | CSR rowptr
__global__ __launch_bounds__(256) void prep_kernel(const float* __restrict__ x,
                                                   u16* __restrict__ xd,
                                                   const float* __restrict__ W,
                                                   u16* __restrict__ WbT,
                                                   const int* __restrict__ dst,
                                                   int* __restrict__ rowptr) {
  int b = blockIdx.x;
  if (b < DROP_BLKS) {
    // dropout: 8 consecutive flat elements per thread (RNG index = flat index)
    int t = b * 256 + threadIdx.x;
    int j0 = t * 8;
    float4 xa = *(const float4*)(x + j0);
    float4 xb = *(const float4*)(x + j0 + 4);
    float xs[8] = {xa.x, xa.y, xa.z, xa.w, xb.x, xb.y, xb.z, xb.w};
    u16 r[8];
#pragma unroll
    for (int q = 0; q < 8; ++q) {
      u32 a = 0u, c = (u32)(j0 + q);
      threefry(a, c);
      u32 bits = a ^ c;
      float u = __uint_as_float((bits >> 9) | 0x3F800000u) - 1.0f;  // [0,1)
      float m = (u < 0.9f) ? (1.0f / 0.9f) : 0.0f;
      r[q] = f2bf(xs[q] * m);
    }
    uint4 o;
    o.x = (u32)r[0] | ((u32)r[1] << 16);
    o.y = (u32)r[2] | ((u32)r[3] << 16);
    o.z = (u32)r[4] | ((u32)r[5] << 16);
    o.w = (u32)r[6] | ((u32)r[7] << 16);
    *(uint4*)(xd + j0) = o;
  } else if (b < DROP_BLKS + WCONV_BLKS) {
    // W [k][n] fp32 -> WbT [n][k] bf16
    int t = (b - DROP_BLKS) * 256 + threadIdx.x;   // 0..262143
    int k = t >> 9, n = t & 511;
    WbT[n * 512 + k] = f2bf(W[t]);
  } else {
    // CSR rowptr from sorted dst (covers [0,N] exactly once)
    int e = (b - DROP_BLKS - WCONV_BLKS) * 256 + threadIdx.x;
    if (e > N_EDGESC) return;
    int d  = (e < N_EDGESC) ? dst[e] : N_NODESC;
    int pd = (e > 0) ? dst[e - 1] : -1;
    for (int n = pd + 1; n <= d; ++n) rowptr[n] = e;
  }
}

// 2) aggregation v6: persistent grid, static strided wave->node map.
//    Per node: full 512-feat row across 64 lanes (uint4 = 16B/lane, 1KB
//    coalesced per edge), 8-deep load ladder.
__device__ __forceinline__ void agg_fma(float* acc, float w, const uint4& v) {
  u32 a[4] = {v.x, v.y, v.z, v.w};
#pragma unroll
  for (int p = 0; p < 4; ++p) {
    acc[2*p]   += w * __uint_as_float(a[p] << 16);
    acc[2*p+1] += w * __uint_as_float(a[p] & 0xFFFF0000u);
  }
}

__global__ __launch_bounds__(256) void agg_kernel(const u16* __restrict__ xd,
                                                  const float* __restrict__ ew,
                                                  const int* __restrict__ src,
                                                  const int* __restrict__ rowptr,
                                                  u16* __restrict__ agg) {
  const int lane = threadIdx.x & 63;
  const int wid  = blockIdx.x * 4 + (threadIdx.x >> 6);   // 0..8191

#pragma unroll 1
  for (int node = wid; node < N_NODESC; node += AGG_WAVES) {
    int lo = rowptr[node];
    int hi = rowptr[node + 1];
    float acc[8] = {0.f,0.f,0.f,0.f,0.f,0.f,0.f,0.f};

    int e = lo;
    for (; e + 8 <= hi; e += 8) {
      uint4 v[8]; float w[8];
#pragma unroll
      for (int q = 0; q < 8; ++q) {
        int s = src[e + q];
        w[q] = ew[e + q];
        v[q] = ((const uint4*)(xd + (size_t)s * FEATS))[lane];
      }
#pragma unroll
      for (int q = 0; q < 8; ++q) agg_fma(acc, w[q], v[q]);
    }
    if (e + 4 <= hi) {
      uint4 v[4]; float w[4];
#pragma unroll
      for (int q = 0; q < 4; ++q) {
        int s = src[e + q];
        w[q] = ew[e + q];
        v[q] = ((const uint4*)(xd + (size_t)s * FEATS))[lane];
      }
#pragma unroll
      for (int q = 0; q < 4; ++q) agg_fma(acc, w[q], v[q]);
      e += 4;
    }
    for (; e < hi; ++e) {
      float w = ew[e];
      int s = src[e];
      uint4 v = ((const uint4*)(xd + (size_t)s * FEATS))[lane];
      agg_fma(acc, w, v);
    }

    uint4 o;
    o.x = (u32)f2bf(acc[0]) | ((u32)f2bf(acc[1]) << 16);
    o.y = (u32)f2bf(acc[2]) | ((u32)f2bf(acc[3]) << 16);
    o.z = (u32)f2bf(acc[4]) | ((u32)f2bf(acc[5]) << 16);
    o.w = (u32)f2bf(acc[6]) | ((u32)f2bf(acc[7]) << 16);
    ((uint4*)(agg + (size_t)node * FEATS))[lane] = o;
  }
}

// 3) GEMM: C[M,512] = A[M,512](bf16) * B^T ; relu(+bias).  (v1 measured-best)
#define BM 128
#define BN 256
#define BK 64

__global__ __launch_bounds__(512, 4) void gemm_kernel(const u16* __restrict__ A,
                                                      const u16* __restrict__ BT,
                                                      const float* __restrict__ bias,
                                                      float* __restrict__ out) {
  __shared__ __align__(16) u16 Asm[BM * BK];   // 16 KB
  __shared__ __align__(16) u16 Bsm[BN * BK];   // 32 KB

  const int tid  = threadIdx.x;
  const int lane = tid & 63;
  const int w    = tid >> 6;          // 0..7
  const int m0 = blockIdx.x * BM;
  const int n0 = blockIdx.y * BN;
  const int wm = (w >> 2) * 64;       // 0,64
  const int wn = (w & 3) * 64;        // 0,64,128,192
  const int lm   = lane & 15;
  const int quad = lane >> 4;
  const int lrow = lane >> 3;        // 0..7
  const int lcol = (lane & 7) * 8;   // bf16 elems

  floatx4 acc[4][4];
#pragma unroll
  for (int i = 0; i < 4; ++i)
#pragma unroll
    for (int j = 0; j < 4; ++j) acc[i][j] = (floatx4)0.0f;

  for (int k0 = 0; k0 < 512; k0 += BK) {
    // A: 16 chunks (8 rows x 64 cols = 1 KB each); 8 waves x 2
#pragma unroll
    for (int t = 0; t < 2; ++t) {
      int chunk = w * 2 + t;              // 0..15
      int row = chunk * 8 + lrow;         // 0..127
      int gm = m0 + row;
      if (gm > N_NODESC - 1) gm = N_NODESC - 1;
      __builtin_amdgcn_global_load_lds(
          (const __attribute__((address_space(1))) void*)(A + (size_t)gm * 512 + k0 + lcol),
          (__attribute__((address_space(3))) void*)((char*)Asm + chunk * 1024),
          16, 0, 0);
    }
    // B: 32 chunks; 8 waves x 4
#pragma unroll
    for (int t = 0; t < 4; ++t) {
      int chunk = w * 4 + t;              // 0..31
      int row = chunk * 8 + lrow;         // 0..255
      __builtin_amdgcn_global_load_lds(
          (const __attribute__((address_space(1))) void*)(BT + (size_t)(n0 + row) * 512 + k0 + lcol),
          (__attribute__((address_space(3))) void*)((char*)Bsm + chunk * 1024),
          16, 0, 0);
    }
    __syncthreads();

#pragma unroll
    for (int kk = 0; kk < BK; kk += 32) {
      short8 af[4], bfr[4];
#pragma unroll
      for (int i = 0; i < 4; ++i)
        af[i] = *(const short8*)(Asm + (wm + i * 16 + lm) * BK + kk + quad * 8);
#pragma unroll
      for (int j = 0; j < 4; ++j)
        bfr[j] = *(const short8*)(Bsm + (wn + j * 16 + lm) * BK + kk + quad * 8);
#pragma unroll
      for (int i = 0; i < 4; ++i)
#pragma unroll
        for (int j = 0; j < 4; ++j)
          acc[i][j] = __builtin_amdgcn_mfma_f32_16x16x32_bf16(af[i], bfr[j], acc[i][j], 0, 0, 0);
    }
    __syncthreads();
  }

  // epilogue: C/D layout col=lane&15, row=quad*4+r
#pragma unroll
  for (int j = 0; j < 4; ++j) {
    int col = n0 + wn + j * 16 + lm;
    float bv = bias[col];
#pragma unroll
    for (int i = 0; i < 4; ++i) {
      int row0 = m0 + wm + i * 16 + quad * 4;
#pragma unroll
      for (int r = 0; r < 4; ++r) {
        int row = row0 + r;
        if (row < N_NODESC) {
          float v = acc[i][j][r] + bv;
          out[(size_t)row * 512 + col] = v > 0.0f ? v : 0.0f;
        }
      }
    }
  }
}

extern "C" void kernel_launch(void* const* d_in, const int* in_sizes, int n_in,
                              void* d_out, int out_size, void* d_ws, size_t ws_size,
                              hipStream_t stream) {
  const float* x  = (const float*)d_in[0];
  const float* ew = (const float*)d_in[1];
  const float* W  = (const float*)d_in[2];
  const float* b  = (const float*)d_in[3];
  const int* esrc = (const int*)d_in[4];
  const int* edst = (const int*)d_in[5];
  float* out = (float*)d_out;

  char* ws = (char*)d_ws;
  u16* xd    = (u16*)ws;                                   // 51.2 MB
  u16* agg   = (u16*)(ws + (size_t)TOT_ELEMS * 2);         // 51.2 MB
  u16* WbT   = (u16*)(ws + (size_t)TOT_ELEMS * 4);         // 0.5 MB
  int* rowp  = (int*)(ws + (size_t)TOT_ELEMS * 4 + 512 * 512 * 2);  // 200 KB
  (void)ws_size; (void)n_in; (void)in_sizes; (void)out_size;

  hipLaunchKernelGGL(prep_kernel,  dim3(PREP_BLKS), dim3(256), 0, stream,
                     x, xd, W, WbT, edst, rowp);
  hipLaunchKernelGGL(agg_kernel,   dim3(AGG_GRID), dim3(256), 0, stream,
                     xd, ew, esrc, rowp, agg);
  hipLaunchKernelGGL(gemm_kernel,  dim3((N_NODESC + BM - 1) / BM, 512 / BN), dim3(512), 0, stream,
                     agg, WbT, b, out);
}

// Round 8
// 359.322 us; speedup vs baseline: 1.6611x; 1.0386x over previous
//
#include <hip/hip_runtime.h>
#include <hip/hip_bf16.h>
#include <stdint.h>

// GCN layer: out = relu(segment_sum(dropout(x)[src]*w, dst) @ W + b)
// N=50000 nodes, E=800000 edges (dst SORTED), F=512 in/out feats.
//
// Pipeline (v7):
//  1) prep_kernel : fused grid-partitioned (v1-exact)
//                   [blk 0..12499]     dropout threefry -> xd bf16 [N,512]
//                   [blk 12500..13523] W fp32 [k][n] -> WbT bf16 [n][k]
//                   [blk 13524..16649] CSR rowptr from sorted edge_dst
//  2) agg_kernel  : v1-EXACT gather (block = 4 nodes, wave per node, full
//                   512-feat row, 8-deep ladder). Measured 112us/376MB —
//                   the empirical floor: 4 structural variants (slicing x2,
//                   fusion, persistent-strided) all matched or regressed.
//  3) gemm_kernel : NEW 2-phase double-buffered MFMA GEMM, BK=32.
//                   1-phase (v1) exposed all staging between barriers;
//                   2-phase issues next tile's global_load_lds BEFORE the
//                   current tile's MFMAs, one barrier per K-step (its
//                   implicit vmcnt(0) drains the in-flight stage).
//                   48KB LDS keeps 3 blocks/CU.
//
// [r7 lesson: occupancy was NOT the agg limiter (41% occ -> slower);
//  3.9TB/s random-row-gather is the machine floor for this pattern.]
// [r2/r4: XCD-affine feature slicing triple-refuted. r3: fusion negative.]

#define N_NODESC 50000
#define N_EDGESC 800000
#define FEATS    512
#define TOT_ELEMS (N_NODESC * FEATS)   // 25,600,000

#define DROP_BLKS   12500              // 25.6M / (256*8)
#define WCONV_BLKS  1024               // 262144 / 256
#define ROWP_BLKS   3126               // ceil(800001/256)
#define PREP_BLKS   (DROP_BLKS + WCONV_BLKS + ROWP_BLKS)

typedef unsigned int u32;
typedef unsigned short u16;
typedef __attribute__((ext_vector_type(8))) short short8;
typedef __attribute__((ext_vector_type(4))) float floatx4;

__device__ __forceinline__ void tf_round(u32& a, u32& b, int r) {
  a += b;
  b = (b << r) | (b >> (32 - r));
  b ^= a;
}

// Threefry-2x32, 20 rounds, key = (0, 42)  — bit-exact vs jax; DO NOT TOUCH.
__device__ __forceinline__ void threefry(u32& x0, u32& x1) {
  const u32 k0 = 0u, k1 = 42u, k2 = 0x1BD11BDAu ^ 0u ^ 42u;
  x0 += k0; x1 += k1;
  tf_round(x0,x1,13); tf_round(x0,x1,15); tf_round(x0,x1,26); tf_round(x0,x1,6);
  x0 += k1; x1 += k2 + 1u;
  tf_round(x0,x1,17); tf_round(x0,x1,29); tf_round(x0,x1,16); tf_round(x0,x1,24);
  x0 += k2; x1 += k0 + 2u;
  tf_round(x0,x1,13); tf_round(x0,x1,15); tf_round(x0,x1,26); tf_round(x0,x1,6);
  x0 += k0; x1 += k1 + 3u;
  tf_round(x0,x1,17); tf_round(x0,x1,29); tf_round(x0,x1,16); tf_round(x0,x1,24);
  x0 += k1; x1 += k2 + 4u;
  tf_round(x0,x1,13); tf_round(x0,x1,15); tf_round(x0,x1,26); tf_round(x0,x1,6);
  x0 += k2; x1 += k0 + 5u;
}

__device__ __forceinline__ u16 f2bf(float f) {  // RNE float->bf16
  u32 u = __float_as_uint(f);
  u32 r = (u + 0x7FFFu + ((u >> 16) & 1u)) >> 16;
  return (u16)r;
}

// 1) fused prep: dropout | W transpose+cast | CSR rowptr  (v1-exact)
__global__ __launch_bounds__(256) void prep_kernel(const float* __restrict__ x,
                                                   u16* __restrict__ xd,
                                                   const float* __restrict__ W,
                                                   u16* __restrict__ WbT,
                                                   const int* __restrict__ dst,
                                                   int* __restrict__ rowptr) {
  int b = blockIdx.x;
  if (b < DROP_BLKS) {
    // dropout: 8 consecutive flat elements per thread
    int t = b * 256 + threadIdx.x;
    int j0 = t * 8;
    float4 xa = *(const float4*)(x + j0);
    float4 xb = *(const float4*)(x + j0 + 4);
    float xs[8] = {xa.x, xa.y, xa.z, xa.w, xb.x, xb.y, xb.z, xb.w};
    u16 r[8];
#pragma unroll
    for (int q = 0; q < 8; ++q) {
      u32 a = 0u, c = (u32)(j0 + q);
      threefry(a, c);
      u32 bits = a ^ c;
      float u = __uint_as_float((bits >> 9) | 0x3F800000u) - 1.0f;  // [0,1)
      float m = (u < 0.9f) ? (1.0f / 0.9f) : 0.0f;
      r[q] = f2bf(xs[q] * m);
    }
    uint4 o;
    o.x = (u32)r[0] | ((u32)r[1] << 16);
    o.y = (u32)r[2] | ((u32)r[3] << 16);
    o.z = (u32)r[4] | ((u32)r[5] << 16);
    o.w = (u32)r[6] | ((u32)r[7] << 16);
    *(uint4*)(xd + j0) = o;
  } else if (b < DROP_BLKS + WCONV_BLKS) {
    // W [k][n] fp32 -> WbT [n][k] bf16
    int t = (b - DROP_BLKS) * 256 + threadIdx.x;   // 0..262143
    int k = t >> 9, n = t & 511;
    WbT[n * 512 + k] = f2bf(W[t]);
  } else {
    // CSR rowptr from sorted dst (covers [0,N] exactly once)
    int e = (b - DROP_BLKS - WCONV_BLKS) * 256 + threadIdx.x;
    if (e > N_EDGESC) return;
    int d  = (e < N_EDGESC) ? dst[e] : N_NODESC;
    int pd = (e > 0) ? dst[e - 1] : -1;
    for (int n = pd + 1; n <= d; ++n) rowptr[n] = e;
  }
}

// 2) aggregation: v1-EXACT. 4 nodes per 256-thread block, one wave per node.
__device__ __forceinline__ void agg_fma(float* acc, float w, const uint4& v) {
  u32 a[4] = {v.x, v.y, v.z, v.w};
#pragma unroll
  for (int p = 0; p < 4; ++p) {
    acc[2*p]   += w * __uint_as_float(a[p] << 16);
    acc[2*p+1] += w * __uint_as_float(a[p] & 0xFFFF0000u);
  }
}

__global__ __launch_bounds__(256) void agg_kernel(const u16* __restrict__ xd,
                                                  const float* __restrict__ ew,
                                                  const int* __restrict__ src,
                                                  const int* __restrict__ rowptr,
                                                  u16* __restrict__ agg) {
  int node = blockIdx.x * 4 + (threadIdx.x >> 6);
  if (node >= N_NODESC) return;
  int lane = threadIdx.x & 63;
  int lo = rowptr[node];
  int hi = rowptr[node + 1];
  float acc[8] = {0.f,0.f,0.f,0.f,0.f,0.f,0.f,0.f};

  int e = lo;
  for (; e + 8 <= hi; e += 8) {
    uint4 v[8]; float w[8];
#pragma unroll
    for (int q = 0; q < 8; ++q) {
      int s = src[e + q];
      w[q] = ew[e + q];
      v[q] = ((const uint4*)(xd + (size_t)s * FEATS))[lane];
    }
#pragma unroll
    for (int q = 0; q < 8; ++q) agg_fma(acc, w[q], v[q]);
  }
  if (e + 4 <= hi) {
    uint4 v[4]; float w[4];
#pragma unroll
    for (int q = 0; q < 4; ++q) {
      int s = src[e + q];
      w[q] = ew[e + q];
      v[q] = ((const uint4*)(xd + (size_t)s * FEATS))[lane];
    }
#pragma unroll
    for (int q = 0; q < 4; ++q) agg_fma(acc, w[q], v[q]);
    e += 4;
  }
  for (; e < hi; ++e) {
    float w = ew[e];
    int s = src[e];
    uint4 v = ((const uint4*)(xd + (size_t)s * FEATS))[lane];
    agg_fma(acc, w, v);
  }

  uint4 o;
  o.x = (u32)f2bf(acc[0]) | ((u32)f2bf(acc[1]) << 16);
  o.y = (u32)f2bf(acc[2]) | ((u32)f2bf(acc[3]) << 16);
  o.z = (u32)f2bf(acc[4]) | ((u32)f2bf(acc[5]) << 16);
  o.w = (u32)f2bf(acc[6]) | ((u32)f2bf(acc[7]) << 16);
  ((uint4*)(agg + (size_t)node * FEATS))[lane] = o;
}

// 3) GEMM v7: C[M,512] = A[M,512](bf16) * B^T ; relu(+bias).
//    128x256 tile, 512 thr = 8 waves (2x4 grid of 64x64 wave-tiles, 4x4
//    frags). BK=32, DOUBLE-BUFFERED: per K-step, issue next tile's
//    global_load_lds, then MFMA on current buffer, then one __syncthreads
//    (implicit vmcnt(0) drains the prefetch). Staging overlaps compute.
#define BM 128
#define BN 256
#define BK 32

__global__ __launch_bounds__(512, 4) void gemm_kernel(const u16* __restrict__ A,
                                                      const u16* __restrict__ BT,
                                                      const float* __restrict__ bias,
                                                      float* __restrict__ out) {
  __shared__ __align__(16) u16 Asm[2][BM * BK];   // 2 x 8 KB
  __shared__ __align__(16) u16 Bsm[2][BN * BK];   // 2 x 16 KB  (48 KB total)

  const int tid  = threadIdx.x;
  const int lane = tid & 63;
  const int w    = tid >> 6;          // 0..7
  const int m0 = blockIdx.x * BM;
  const int n0 = blockIdx.y * BN;
  const int wm = (w >> 2) * 64;       // 0,64
  const int wn = (w & 3) * 64;        // 0,64,128,192
  const int lm   = lane & 15;
  const int quad = lane >> 4;
  // staging lane decomposition: lane i covers row i>>2, 16B col-chunk i&3
  const int srow = lane >> 2;         // 0..15
  const int scol = (lane & 3) * 8;    // u16 elems (16B chunks)

  // A-staging row for this wave: rows w*16 + srow; clamp against N
  int a_gm = m0 + w * 16 + srow;
  if (a_gm > N_NODESC - 1) a_gm = N_NODESC - 1;
  const u16* a_src = A + (size_t)a_gm * 512 + scol;
  // B-staging rows: chunk t in {0,1} -> rows w*32 + t*16 + srow
  const u16* b_src0 = BT + (size_t)(n0 + w * 32 + srow) * 512 + scol;
  const u16* b_src1 = BT + (size_t)(n0 + w * 32 + 16 + srow) * 512 + scol;

#define STAGE(buf, k0)                                                        \
  do {                                                                        \
    __builtin_amdgcn_global_load_lds(                                         \
        (const __attribute__((address_space(1))) void*)(a_src + (k0)),        \
        (__attribute__((address_space(3))) void*)((char*)Asm[buf] + w * 1024 + lane * 16), \
        16, 0, 0);                                                            \
    __builtin_amdgcn_global_load_lds(                                         \
        (const __attribute__((address_space(1))) void*)(b_src0 + (k0)),       \
        (__attribute__((address_space(3))) void*)((char*)Bsm[buf] + (w * 2) * 1024 + lane * 16), \
        16, 0, 0);                                                            \
    __builtin_amdgcn_global_load_lds(                                         \
        (const __attribute__((address_space(1))) void*)(b_src1 + (k0)),       \
        (__attribute__((address_space(3))) void*)((char*)Bsm[buf] + (w * 2 + 1) * 1024 + lane * 16), \
        16, 0, 0);                                                            \
  } while (0)

  floatx4 acc[4][4];
#pragma unroll
  for (int i = 0; i < 4; ++i)
#pragma unroll
    for (int j = 0; j < 4; ++j) acc[i][j] = (floatx4)0.0f;

  // prologue: fill buffer 0
  STAGE(0, 0);
  __syncthreads();

#pragma unroll 1
  for (int t = 0; t < 512 / BK; ++t) {
    const int cur = t & 1;
    if (t < 512 / BK - 1) STAGE(cur ^ 1, (t + 1) * BK);   // prefetch next

    short8 af[4], bfr[4];
#pragma unroll
    for (int i = 0; i < 4; ++i)
      af[i] = *(const short8*)(Asm[cur] + (wm + i * 16 + lm) * BK + quad * 8);
#pragma unroll
    for (int j = 0; j < 4; ++j)
      bfr[j] = *(const short8*)(Bsm[cur] + (wn + j * 16 + lm) * BK + quad * 8);
#pragma unroll
    for (int i = 0; i < 4; ++i)
#pragma unroll
      for (int j = 0; j < 4; ++j)
        acc[i][j] = __builtin_amdgcn_mfma_f32_16x16x32_bf16(af[i], bfr[j], acc[i][j], 0, 0, 0);

    __syncthreads();   // drains prefetch (vmcnt 0) + guards cur-buf reuse
  }
#undef STAGE

  // epilogue: C/D layout col=lane&15, row=quad*4+r
#pragma unroll
  for (int j = 0; j < 4; ++j) {
    int col = n0 + wn + j * 16 + lm;
    float bv = bias[col];
#pragma unroll
    for (int i = 0; i < 4; ++i) {
      int row0 = m0 + wm + i * 16 + quad * 4;
#pragma unroll
      for (int r = 0; r < 4; ++r) {
        int row = row0 + r;
        if (row < N_NODESC) {
          float v = acc[i][j][r] + bv;
          out[(size_t)row * 512 + col] = v > 0.0f ? v : 0.0f;
        }
      }
    }
  }
}

extern "C" void kernel_launch(void* const* d_in, const int* in_sizes, int n_in,
                              void* d_out, int out_size, void* d_ws, size_t ws_size,
                              hipStream_t stream) {
  const float* x  = (const float*)d_in[0];
  const float* ew = (const float*)d_in[1];
  const float* W  = (const float*)d_in[2];
  const float* b  = (const float*)d_in[3];
  const int* esrc = (const int*)d_in[4];
  const int* edst = (const int*)d_in[5];
  float* out = (float*)d_out;

  char* ws = (char*)d_ws;
  u16* xd    = (u16*)ws;                                   // 51.2 MB
  u16* agg   = (u16*)(ws + (size_t)TOT_ELEMS * 2);         // 51.2 MB
  u16* WbT   = (u16*)(ws + (size_t)TOT_ELEMS * 4);         // 0.5 MB
  int* rowp  = (int*)(ws + (size_t)TOT_ELEMS * 4 + 512 * 512 * 2);  // 200 KB
  (void)ws_size; (void)n_in; (void)in_sizes; (void)out_size;

  hipLaunchKernelGGL(prep_kernel,  dim3(PREP_BLKS), dim3(256), 0, stream,
                     x, xd, W, WbT, edst, rowp);
  hipLaunchKernelGGL(agg_kernel,   dim3((N_NODESC + 3) / 4), dim3(256), 0, stream,
                     xd, ew, esrc, rowp, agg);
  hipLaunchKernelGGL(gemm_kernel,  dim3((N_NODESC + BM - 1) / BM, 512 / BN), dim3(512), 0, stream,
                     agg, WbT, b, out);
}